// Round 6
// baseline (503.136 us; speedup 1.0000x reference)
//
#include <hip/hip_runtime.h>
#include <hip/hip_bf16.h>

#define DM 512
#define BCN 2048
#define XPATCH ((size_t)BCN * 64 * DM)     // 67,108,864 floats

typedef float f32x8 __attribute__((ext_vector_type(8)));

__device__ __forceinline__ unsigned pack_bf16(float a, float b) {
    __hip_bfloat162 h = __float22bfloat162_rn(make_float2(a, b));
    return *reinterpret_cast<unsigned*>(&h);
}
__device__ __forceinline__ float2 unpack_bf16(unsigned p) {
    float2 r;
    r.x = __uint_as_float(p << 16);
    r.y = __uint_as_float(p & 0xffff0000u);
    return r;
}

// Launder a wave-uniform pointer into SGPRs so "s" constraints allocate.
__device__ __forceinline__ const float* uniform_ptr(const float* p) {
    unsigned long long v = (unsigned long long)p;
    unsigned lo = __builtin_amdgcn_readfirstlane((unsigned)v);
    unsigned hi = __builtin_amdgcn_readfirstlane((unsigned)(v >> 32));
    return (const float*)(((unsigned long long)hi << 32) | lo);
}

// Issue-only SMEM loads (no wait): enables depth-2 software pipelining.
__device__ __forceinline__ void sload32_issue(const float* p, f32x8& a, f32x8& b,
                                              f32x8& c, f32x8& d) {
    asm volatile(
        "s_load_dwordx8 %0, %4, 0x0\n\t"
        "s_load_dwordx8 %1, %4, 0x20\n\t"
        "s_load_dwordx8 %2, %4, 0x40\n\t"
        "s_load_dwordx8 %3, %4, 0x60"
        : "=&s"(a), "=&s"(b), "=&s"(c), "=&s"(d)
        : "s"(uniform_ptr(p)));
}
__device__ __forceinline__ void sload3_issue(const float* p, float& a, float& b, float& c) {
    asm volatile(
        "s_load_dword %0, %3, 0x0\n\t"
        "s_load_dword %1, %3, 0x4\n\t"
        "s_load_dword %2, %3, 0x8"
        : "=&s"(a), "=&s"(b), "=&s"(c)
        : "s"(uniform_ptr(p)));
}
// Wait for outstanding SMEM; sched_barrier stops hipcc hoisting consumers
// above the wait (rule #18: "memory" clobber does not order register-only ops).
__device__ __forceinline__ void swait() {
    asm volatile("s_waitcnt lgkmcnt(0)" ::: "memory");
    __builtin_amdgcn_sched_barrier(0);
}

// 64-lane sum via DPP (VALU pipe), uniform result (verified R3/R5).
template<int CTRL>
__device__ __forceinline__ float dpp_add(float x) {
    int mv = __builtin_amdgcn_update_dpp(0, __float_as_int(x), CTRL, 0xf, 0xf, false);
    return x + __int_as_float(mv);
}
__device__ __forceinline__ float wave_sum(float x) {
    x = dpp_add<0x111>(x);   // row_shr:1
    x = dpp_add<0x112>(x);   // row_shr:2
    x = dpp_add<0x114>(x);   // row_shr:4
    x = dpp_add<0x118>(x);   // row_shr:8
    x = dpp_add<0x142>(x);   // row_bcast:15
    x = dpp_add<0x143>(x);   // row_bcast:31
    return __int_as_float(__builtin_amdgcn_readlane(__float_as_int(x), 63));
}

// Dot of 8 consecutive x values (SGPR f32x8) with 4 packed-bf16 weight pairs.
__device__ __forceinline__ float dot8p(const f32x8& v, const unsigned* wp, float acc) {
    #pragma unroll
    for (int j = 0; j < 4; ++j) {
        float2 w = unpack_bf16(wp[j]);
        acc = fmaf(v[2 * j],     w.x, acc);
        acc = fmaf(v[2 * j + 1], w.y, acc);
    }
    return acc;
}

// Grid: 2048 blocks x 256 threads. Block = (bc-pair, col-half):
//   bid>>1 = bc pair, bid&1 = which 256 output columns. 2 bc per block.
// Thread owns ONE column; expert weights live in 28 packed-bf16 VGPRs
// (classifier w1/w2 stay fp32 -> expert choice exact). x + gumbel arrive via
// depth-2 software-pipelined s_load (issue r+1 before computing r) so the
// SMEM latency hides under compute instead of 18 serialized waits per bc.
// __launch_bounds__(256,5): VGPR<=102 -> 5 blocks/CU = 20 waves/CU (R5 had 16).
// Phase B touches no vector loads and no LDS; stores are fire-and-forget.
__global__ __launch_bounds__(256, 5) void ape_fused(
    const float* __restrict__ x,
    const float* __restrict__ gumbel,
    const float* __restrict__ w1,
    const float* __restrict__ b1,
    const float* __restrict__ w2,
    const float* __restrict__ b2,
    const float* __restrict__ w8,
    const float* __restrict__ w16,
    const float* __restrict__ w32,
    float* __restrict__ out)
{
    __shared__ int eidx[2][16];

    const int tid  = threadIdx.x;
    const int lane = tid & 63;
    const int wv   = tid >> 6;             // wave 0..3
    const int hf   = blockIdx.x & 1;       // column half
    const int bc0  = (blockIdx.x >> 1) * 2;
    const int col  = tid + (hf << 8);      // owned output column 0..511

    // ---- per-thread packed expert weights (bf16 pairs), coalesced loads ----
    unsigned w8p[4], w16p[8], w32p[16];
    #pragma unroll
    for (int j = 0; j < 4; ++j)
        w8p[j]  = pack_bf16(w8 [(size_t)(2*j) * DM + col], w8 [(size_t)(2*j+1) * DM + col]);
    #pragma unroll
    for (int j = 0; j < 8; ++j)
        w16p[j] = pack_bf16(w16[(size_t)(2*j) * DM + col], w16[(size_t)(2*j+1) * DM + col]);
    #pragma unroll
    for (int j = 0; j < 16; ++j)
        w32p[j] = pack_bf16(w32[(size_t)(2*j) * DM + col], w32[(size_t)(2*j+1) * DM + col]);

    // ---- classifier weights: fp32 (expert selection must match reference) ----
    float w1r[32];
    #pragma unroll
    for (int q = 0; q < 32; ++q) w1r[q] = w1[q * 64 + lane];
    const float b1r  = b1[lane];
    const float w2r0 = w2[lane * 3 + 0];
    const float w2r1 = w2[lane * 3 + 1];
    const float w2r2 = w2[lane * 3 + 2];
    const float b20  = b2[0], b21 = b2[1], b22 = b2[2];

    // ---- PE per-column constants: pe[pos,col] = sin(pos*dv + (col&1)*pi/2) ----
    const float kln = -9.210340371976184f / 256.0f;   // -ln(10000)/256
    const float dv  = __expf(kln * (float)(col >> 1));
    const float ph  = (col & 1) ? 1.5707963267948966f : 0.0f;

    #pragma unroll 1
    for (int i = 0; i < 2; ++i) {
        const int bc = bc0 + i;
        const float* __restrict__ xrow = x + (size_t)bc * DM;
        int* ei = eidx[i];                 // double buffer: 1 barrier per bc

        auto classify = [&](int rr, const f32x8& va, const f32x8& vb,
                            const f32x8& vc, const f32x8& vd,
                            float g0, float g1, float g2) {
            float a = b1r;
            #pragma unroll
            for (int q = 0; q < 8; ++q) {
                a = fmaf(va[q], w1r[q],      a);
                a = fmaf(vb[q], w1r[8 + q],  a);
                a = fmaf(vc[q], w1r[16 + q], a);
                a = fmaf(vd[q], w1r[24 + q], a);
            }
            const float h = fmaxf(a, 0.f);
            float s0 = wave_sum(h * w2r0) + b20 + g0;
            float s1 = wave_sum(h * w2r1) + b21 + g1;
            float s2 = wave_sum(h * w2r2) + b22 + g2;
            int best = 0; float bs = s0;
            if (s1 > bs) { bs = s1; best = 1; }
            if (s2 > bs) best = 2;
            if (lane == 0) {
                ei[rr] = best;
                if (hf == 0)
                    out[XPATCH + (size_t)rr * BCN + bc] = (float)best;
            }
        };

        // ---- Phase A: wave wv owns regions 4wv..4wv+3; depth-2 pipeline ----
        {
            const int r0 = wv * 4;
            const float* gb = gumbel + ((size_t)bc * 16 + r0) * 3;
            f32x8 pa, pb, pc, pd, qa, qb, qc, qd;
            float pg0, pg1, pg2, qg0, qg1, qg2;
            sload32_issue(xrow + r0 * 32, pa, pb, pc, pd);
            sload3_issue(gb, pg0, pg1, pg2);

            swait();
            sload32_issue(xrow + (r0 + 1) * 32, qa, qb, qc, qd);
            sload3_issue(gb + 3, qg0, qg1, qg2);
            classify(r0 + 0, pa, pb, pc, pd, pg0, pg1, pg2);

            swait();
            sload32_issue(xrow + (r0 + 2) * 32, pa, pb, pc, pd);
            sload3_issue(gb + 6, pg0, pg1, pg2);
            classify(r0 + 1, qa, qb, qc, qd, qg0, qg1, qg2);

            swait();
            sload32_issue(xrow + (r0 + 3) * 32, qa, qb, qc, qd);
            sload3_issue(gb + 9, qg0, qg1, qg2);
            classify(r0 + 2, pa, pb, pc, pd, pg0, pg1, pg2);

            swait();
            classify(r0 + 3, qa, qb, qc, qd, qg0, qg1, qg2);
        }
        __syncthreads();                   // eidx visible; only barrier per bc

        // ---- gather expert ids into one SGPR (no LDS in the B loop) ----
        unsigned ep = 0;
        #pragma unroll
        for (int r = 0; r < 16; ++r) ep |= ((unsigned)(ei[r] & 3)) << (2 * r);
        ep = (unsigned)__builtin_amdgcn_readfirstlane((int)ep);

        auto regB = [&](int rr, const f32x8& va, const f32x8& vb,
                        const f32x8& vc, const f32x8& vd) {
            const int e = (int)((ep >> (2 * rr)) & 3u);
            float a0, a1, a2, a3;
            if (e == 0) {                  // p=8: 4 distinct dots of len 8
                a0 = dot8p(va, w8p, 0.f);
                a1 = dot8p(vb, w8p, 0.f);
                a2 = dot8p(vc, w8p, 0.f);
                a3 = dot8p(vd, w8p, 0.f);
            } else if (e == 1) {           // p=16: rows 0..2 patch0, row 3 patch1
                float d0 = dot8p(vb, w16p + 4, dot8p(va, w16p, 0.f));
                float d1 = dot8p(vd, w16p + 4, dot8p(vc, w16p, 0.f));
                a0 = a1 = a2 = d0; a3 = d1;
            } else {                       // p=32: 1 dot of len 32
                float d = dot8p(vd, w32p + 12,
                          dot8p(vc, w32p + 8,
                          dot8p(vb, w32p + 4,
                          dot8p(va, w32p, 0.f))));
                a0 = a1 = a2 = a3 = d;
            }
            const size_t ob   = ((size_t)(bc * 64 + rr * 4)) * DM + col;
            const float  base = (float)(rr * 4) * dv + ph;
            out[ob]          = a0 + __sinf(base);
            out[ob +     DM] = a1 + __sinf(base + dv);
            out[ob + 2 * DM] = a2 + __sinf(base + 2.f * dv);
            out[ob + 3 * DM] = a3 + __sinf(base + 3.f * dv);
        };

        // ---- Phase B: 16 regions, depth-2 pipelined s_loads, stores unwaited ----
        {
            f32x8 Aa, Ab, Ac, Ad, Ba, Bb, Bc, Bd;
            sload32_issue(xrow, Aa, Ab, Ac, Ad);
            #pragma unroll 1
            for (int r2 = 0; r2 < 8; ++r2) {
                const int ra = r2 * 2;
                swait();
                sload32_issue(xrow + (ra + 1) * 32, Ba, Bb, Bc, Bd);
                regB(ra, Aa, Ab, Ac, Ad);
                swait();
                if (r2 < 7)
                    sload32_issue(xrow + (ra + 2) * 32, Aa, Ab, Ac, Ad);
                regB(ra + 1, Ba, Bb, Bc, Bd);
            }
        }
    }
}

extern "C" void kernel_launch(void* const* d_in, const int* in_sizes, int n_in,
                              void* d_out, int out_size, void* d_ws, size_t ws_size,
                              hipStream_t stream) {
    const float* x      = (const float*)d_in[0];
    const float* gumbel = (const float*)d_in[1];
    const float* w1     = (const float*)d_in[2];
    const float* b1     = (const float*)d_in[3];
    const float* w2     = (const float*)d_in[4];
    const float* b2     = (const float*)d_in[5];
    const float* w8     = (const float*)d_in[6];
    const float* w16    = (const float*)d_in[7];
    const float* w32    = (const float*)d_in[8];
    float* out = (float*)d_out;

    ape_fused<<<2048, 256, 0, stream>>>(x, gumbel, w1, b1, w2, b2, w8, w16, w32, out);
}